// Round 6
// baseline (1037.394 us; speedup 1.0000x reference)
//
#include <hip/hip_runtime.h>
#include <cstdint>
#include <cstddef>

typedef unsigned short u16;
typedef __bf16 bf16x8 __attribute__((ext_vector_type(8)));
typedef float  f32x4  __attribute__((ext_vector_type(4)));
typedef u16    u16x4  __attribute__((ext_vector_type(4)));

__device__ __forceinline__ void splitv(const float4 a, const float4 b, bf16x8& h, bf16x8& l) {
    float x[8] = {a.x, a.y, a.z, a.w, b.x, b.y, b.z, b.w};
#pragma unroll
    for (int i = 0; i < 8; i++) {
        __bf16 hh = (__bf16)x[i];
        h[i] = hh;
        l[i] = (__bf16)(x[i] - (float)hh);   // exact residual in fp32
    }
}
__device__ __forceinline__ void hiv(const float4 a, const float4 b, bf16x8& h) {
    float x[8] = {a.x, a.y, a.z, a.w, b.x, b.y, b.z, b.w};
#pragma unroll
    for (int i = 0; i < 8; i++) h[i] = (__bf16)x[i];
}

// async global->LDS, 16B per lane. LDS dest = wave-uniform base + lane*16.
__device__ __forceinline__ void gl16(const void* g, void* l) {
    __builtin_amdgcn_global_load_lds((__attribute__((address_space(1))) void*)g,
                                     (__attribute__((address_space(3))) void*)l, 16, 0, 0);
}

// Section modes: mode==0 -> fp32 source, in-kernel split (raw inputs, first use only);
//                mode==1 -> pre-split bf16 h (+l for NP==3), staged via global_load_lds.
struct Sec {
    const void* h;   // fp32 base (mode 0) or bf16-hi base (mode 1)
    const u16*  l;   // bf16-lo base (mode 1, NP==3)
    int lda; int mode;
};
struct GemmArgs {
    Sec A0[4]; Sec A1[4];                  // per-half A sections
    const u16* B0h; const u16* B0l;        // pre-split weights per half
    const u16* B1h; const u16* B1l;
    const float* bias0; const float* bias1;
    float* Z0; float* Z1;                  // fp32 out (zmode 0)
    u16* Zh0; u16* Zl0; u16* Zh1; u16* Zl1;// bf16 out (zmode 1: h, zmode 2: h+l)
    int bk[4];                             // per-section K offset into B rows
    int nsec, ldb, N, spsl, relu, zmode;
};

// ---- GEMM v7: v6's 128x128 dbuf tile + T4 counted-vmcnt pipeline.
// v6 post-mortem: 4787 cyc/step vs 1863 MFMA-pipe demand -> ~2900 cyc stall; the
// __syncthreads vmcnt(0)-drain exposes staging latency (compiler free to sink the
// result-less gl16 issues toward the barrier). v7 per step:
//   issue stage(t+1)->buf[nxt]  (gl16 / writeA0+regload)
//   s_waitcnt vmcnt(N)   N = #vmem just issued  => only OLDER loads must land (never 0
//                        in steady state; the wait doubles as an issue-order fence)
//   s_waitcnt lgkmcnt(0); s_barrier        => buf[cur] visible to all waves
//   compute(t) from buf[cur]  (setprio(1) around MFMA cluster)
//   s_barrier                               => all reads of buf[cur] done; next step may
//                                              stage into it
// Numerically identical to v6 (same MFMA order). LDS np3 2x32KB -> 2 blocks/CU.
template <int NP>
__global__ __launch_bounds__(256, 2) void gemm_v7(GemmArgs p) {
    constexpr bool NP3 = (NP == 3);
    __shared__ __align__(16) u16 AhS[2][4096];                    // 128 x 32
    __shared__ __align__(16) u16 BhS[2][4096];                    // 128 x 32
    __shared__ __align__(16) u16 AlS[NP3 ? 2 : 1][NP3 ? 4096 : 8];
    __shared__ __align__(16) u16 BlS[NP3 ? 2 : 1][NP3 ? 4096 : 8];

    const int tid = threadIdx.x;
    const int lin = blockIdx.x;
    const int mt = ((lin & 7) << 2) | ((lin >> 3) & 3);
    const int nt = lin >> 5;
    const int NTh = p.N >> 7;
    const int half = (nt >= NTh) ? 1 : 0;
    const int n0 = (nt - (half ? NTh : 0)) * 128;
    const int m0 = mt * 128;
    const u16* Bwh = half ? p.B1h : p.B0h;
    const u16* Bwl = half ? p.B1l : p.B0l;
    const float* bia = half ? p.bias1 : p.bias0;
    float* Z = half ? p.Z1 : p.Z0;
    u16* Zh = half ? p.Zh1 : p.Zh0;
    u16* Zl = half ? p.Zl1 : p.Zl0;
    const Sec* As = half ? p.A1 : p.A0;

    const int wave = tid >> 6, lane = tid & 63;
    const int quad = lane >> 4, lr = lane & 15;
    const int wm = (wave & 1) * 64, wn = (wave >> 1) * 64;

    f32x4 acc[4][4];
#pragma unroll
    for (int i = 0; i < 4; i++)
#pragma unroll
        for (int j = 0; j < 4; j++) acc[i][j] = (f32x4){0.f, 0.f, 0.f, 0.f};

    // staging geometry: thread covers rows arow/arow+64, slot aslot (16B slots of 64B rows)
    const int arow = tid >> 2;
    const int aslot = tid & 3;
    const int csw = aslot ^ ((arow ^ (arow >> 2)) & 3);     // swizzled slot (same for row+64)
    const int wr_i0 = arow * 32 + csw * 8;                  // u16 index for fp32-mode LDS write
    const int ldsw = wave * 1024;                           // wave-uniform byte base for gl16
    // read-side swizzle: logical slot = quad, row term = (lr ^ lr>>2)&3 (wm/wn mult of 64)
    const int qx8 = ((quad ^ ((lr ^ (lr >> 2)) & 3)) & 3) * 8;

    const int sps = 1 << p.spsl;
    const int total = p.nsec << p.spsl;

    float4 v0a{}, v0b{}, v1a{}, v1b{};

    auto regload = [&](const Sec& sec, int t) {
        const float* a0 = (const float*)sec.h + (size_t)(m0 + arow) * sec.lda + t * 32 + aslot * 8;
        v0a = ((const float4*)a0)[0]; v0b = ((const float4*)a0)[1];
        const float* a1 = a0 + (size_t)64 * sec.lda;
        v1a = ((const float4*)a1)[0]; v1b = ((const float4*)a1)[1];
    };
    auto writeA0 = [&](int buf) {
        if constexpr (NP3) {
            bf16x8 h, l;
            splitv(v0a, v0b, h, l);
            *(bf16x8*)&AhS[buf][wr_i0] = h;        *(bf16x8*)&AlS[buf][wr_i0] = l;
            splitv(v1a, v1b, h, l);
            *(bf16x8*)&AhS[buf][2048 + wr_i0] = h; *(bf16x8*)&AlS[buf][2048 + wr_i0] = l;
        } else {
            bf16x8 h;
            hiv(v0a, v0b, h); *(bf16x8*)&AhS[buf][wr_i0] = h;
            hiv(v1a, v1b, h); *(bf16x8*)&AhS[buf][2048 + wr_i0] = h;
        }
    };
    auto stageA1 = [&](int buf, const Sec& sec, int t) {
        const u16* gh = (const u16*)sec.h;
        const size_t o0 = (size_t)(m0 + arow) * sec.lda + t * 32 + csw * 8;
        const size_t o1 = o0 + (size_t)64 * sec.lda;
        gl16(gh + o0, (char*)&AhS[buf][0] + ldsw);
        gl16(gh + o1, (char*)&AhS[buf][0] + 4096 + ldsw);
        if constexpr (NP3) {
            gl16(sec.l + o0, (char*)&AlS[buf][0] + ldsw);
            gl16(sec.l + o1, (char*)&AlS[buf][0] + 4096 + ldsw);
        }
    };
    auto stageB = [&](int buf, int s, int t) {
        const size_t o0 = (size_t)(n0 + arow) * p.ldb + p.bk[s] + t * 32 + csw * 8;
        const size_t o1 = o0 + (size_t)64 * p.ldb;
        gl16(Bwh + o0, (char*)&BhS[buf][0] + ldsw);
        gl16(Bwh + o1, (char*)&BhS[buf][0] + 4096 + ldsw);
        if constexpr (NP3) {
            gl16(Bwl + o0, (char*)&BlS[buf][0] + ldsw);
            gl16(Bwl + o1, (char*)&BlS[buf][0] + 4096 + ldsw);
        }
    };

    // ---- prologue: fill buf0 with t=0; prefetch regs for t=1 if that section is fp32 ----
    stageB(0, 0, 0);
    {
        const Sec s0 = As[0];
        if (s0.mode == 0) { regload(s0, 0); writeA0(0); }
        else stageA1(0, s0, 0);
    }
    if (total > 1) {
        const Sec s1 = As[1 >> p.spsl];
        if (s1.mode == 0) regload(s1, 1 & (sps - 1));
    }
    // no wait/barrier here: the loop's first counted wait + barrier covers buf0.

    for (int tt = 0; tt < total; ++tt) {
        const int cur = tt & 1, nxt = cur ^ 1;
        // ---- stage tile tt+1 into buf[nxt]; counted wait (completes all OLDER vmem) ----
        if (tt + 1 < total) {
            const int u = tt + 1, s = u >> p.spsl, t = u & (sps - 1);
            const Sec sec = As[s];
            if (sec.mode == 0) {
                stageB(nxt, s, t);
                if constexpr (NP3) asm volatile("s_waitcnt vmcnt(4)" ::: "memory");
                else               asm volatile("s_waitcnt vmcnt(2)" ::: "memory");
                __builtin_amdgcn_sched_barrier(0);
                writeA0(nxt);                 // regs loaded last step are now complete
                if (tt + 2 < total) {
                    const Sec sec2 = As[(tt + 2) >> p.spsl];
                    if (sec2.mode == 0) regload(sec2, (tt + 2) & (sps - 1));
                }
            } else {
                stageB(nxt, s, t);
                stageA1(nxt, sec, t);
                if constexpr (NP3) asm volatile("s_waitcnt vmcnt(8)" ::: "memory");
                else               asm volatile("s_waitcnt vmcnt(4)" ::: "memory");
                __builtin_amdgcn_sched_barrier(0);
                if (tt + 2 < total) {
                    const Sec sec2 = As[(tt + 2) >> p.spsl];
                    if (sec2.mode == 0) regload(sec2, (tt + 2) & (sps - 1));
                }
            }
        } else {
            asm volatile("s_waitcnt vmcnt(0)" ::: "memory");   // tail: drain everything
            __builtin_amdgcn_sched_barrier(0);
        }
        asm volatile("s_waitcnt lgkmcnt(0)" ::: "memory");     // ds_writes visible
        __builtin_amdgcn_s_barrier();                          // buf[cur] ready for all
        // ---- compute from buf[cur]: each wave 64x64, A-frags reused over 4 B-col tiles ----
        bf16x8 ah[4], bh[4];
#pragma unroll
        for (int i = 0; i < 4; i++)
            ah[i] = *reinterpret_cast<const bf16x8*>(&AhS[cur][(wm + i * 16 + lr) * 32 + qx8]);
#pragma unroll
        for (int j = 0; j < 4; j++)
            bh[j] = *reinterpret_cast<const bf16x8*>(&BhS[cur][(wn + j * 16 + lr) * 32 + qx8]);
        __builtin_amdgcn_s_setprio(1);
#pragma unroll
        for (int i = 0; i < 4; i++)
#pragma unroll
            for (int j = 0; j < 4; j++)
                acc[i][j] = __builtin_amdgcn_mfma_f32_16x16x32_bf16(ah[i], bh[j], acc[i][j], 0, 0, 0);
        if constexpr (NP3) {
            bf16x8 al[4], bl[4];
#pragma unroll
            for (int i = 0; i < 4; i++)
                al[i] = *reinterpret_cast<const bf16x8*>(&AlS[cur][(wm + i * 16 + lr) * 32 + qx8]);
#pragma unroll
            for (int j = 0; j < 4; j++)
                bl[j] = *reinterpret_cast<const bf16x8*>(&BlS[cur][(wn + j * 16 + lr) * 32 + qx8]);
#pragma unroll
            for (int i = 0; i < 4; i++)
#pragma unroll
                for (int j = 0; j < 4; j++) {
                    acc[i][j] = __builtin_amdgcn_mfma_f32_16x16x32_bf16(ah[i], bl[j], acc[i][j], 0, 0, 0);
                    acc[i][j] = __builtin_amdgcn_mfma_f32_16x16x32_bf16(al[i], bh[j], acc[i][j], 0, 0, 0);
                }
        }
        __builtin_amdgcn_s_setprio(0);
        __builtin_amdgcn_sched_barrier(0);
        __builtin_amdgcn_s_barrier();      // all reads of buf[cur] done (lgkm consumed by MFMAs)
    }

#pragma unroll
    for (int j = 0; j < 4; j++) {
        const int n = n0 + wn + j * 16 + lr;                 // C/D col = lane&15
        const float bj = bia[n];
#pragma unroll
        for (int i = 0; i < 4; i++)
#pragma unroll
            for (int r = 0; r < 4; r++) {
                const int m = m0 + wm + i * 16 + quad * 4 + r;  // C/D row = quad*4+reg
                float v = acc[i][j][r] + bj;
                if (p.relu) v = fmaxf(v, 0.f);
                const size_t zi = (size_t)m * p.N + n;
                if (p.zmode == 0) {
                    Z[zi] = v;
                } else {
                    __bf16 hb = (__bf16)v;
                    Zh[zi] = __builtin_bit_cast(u16, hb);
                    if (p.zmode == 2)
                        Zl[zi] = __builtin_bit_cast(u16, (__bf16)(v - (float)hb));
                }
            }
    }
}

// ---------------- fp32 -> bf16 hi(/lo) conversion (weights), 2 sources per launch ----------------
__global__ __launch_bounds__(256) void conv_split(const float* x0, u16* h0, u16* l0, int n0v,
                                                  const float* x1, u16* h1, u16* l1, int n1v) {
    int i = blockIdx.x * 256 + threadIdx.x;
    const float* x; u16* h; u16* l;
    if (i < n0v) { x = x0; h = h0; l = l0; }
    else { i -= n0v; if (i >= n1v) return; x = x1; h = h1; l = l1; }
    const float4 a = ((const float4*)x)[2 * i], b = ((const float4*)x)[2 * i + 1];
    bf16x8 hh, ll;
    if (l) { splitv(a, b, hh, ll); ((bf16x8*)h)[i] = hh; ((bf16x8*)l)[i] = ll; }
    else   { hiv(a, b, hh);        ((bf16x8*)h)[i] = hh; }
}

__device__ __forceinline__ void store_hl4(const float4 o, u16* hp, u16* lp, int base) {
    float xs[4] = {o.x, o.y, o.z, o.w};
    u16x4 hv, lv;
#pragma unroll
    for (int k = 0; k < 4; k++) {
        __bf16 hb = (__bf16)xs[k];
        hv[k] = __builtin_bit_cast(u16, hb);
        if (lp) lv[k] = __builtin_bit_cast(u16, (__bf16)(xs[k] - (float)hb));
    }
    *(u16x4*)(hp + base) = hv;
    if (lp) *(u16x4*)(lp + base) = lv;
}

// ---------------- elementwise combines (4096x1024): fp32 out + pre-split bf16 out ----------------
__global__ __launch_bounds__(256) void combine1(const float* Z0, const float* Z1, const float* b1in,
                                                float* outr, u16* hO, u16* lO) {
    const int base = (blockIdx.x * 256 + threadIdx.x) * 4;
    const int m = base >> 10;
    const float bf = b1in[2 * m];
    const float4 z0 = *(const float4*)(Z0 + base), z1 = *(const float4*)(Z1 + base);
    float4 o;
    o.x = bf * tanhf(z1.x) + (1.f - bf) * tanhf(z0.x);
    o.y = bf * tanhf(z1.y) + (1.f - bf) * tanhf(z0.y);
    o.z = bf * tanhf(z1.z) + (1.f - bf) * tanhf(z0.z);
    o.w = bf * tanhf(z1.w) + (1.f - bf) * tanhf(z0.w);
    *(float4*)(outr + base) = o;
    store_hl4(o, hO, lO, base);
}
__global__ __launch_bounds__(256) void combine2(const float* Z0, const float* Z1, const float* b2in,
                                                const float* rnn2in, const float* F1, float* outr,
                                                u16* hO, u16* lO) {
    const int base = (blockIdx.x * 256 + threadIdx.x) * 4;
    const int m = base >> 10;
    const float b2f = b2in[2 * m], f1 = F1[m];
    const float4 z0 = *(const float4*)(Z0 + base), z1 = *(const float4*)(Z1 + base);
    const float4 r2 = *(const float4*)(rnn2in + base);
    float4 o;
    o.x = (1.f - f1) * r2.x + f1 * ((1.f - b2f) * tanhf(z0.x) + b2f * tanhf(z1.x));
    o.y = (1.f - f1) * r2.y + f1 * ((1.f - b2f) * tanhf(z0.y) + b2f * tanhf(z1.y));
    o.z = (1.f - f1) * r2.z + f1 * ((1.f - b2f) * tanhf(z0.z) + b2f * tanhf(z1.z));
    o.w = (1.f - f1) * r2.w + f1 * ((1.f - b2f) * tanhf(z0.w) + b2f * tanhf(z1.w));
    *(float4*)(outr + base) = o;
    store_hl4(o, hO, lO, base);
}
__global__ __launch_bounds__(256) void combine3(const float* Z0, const float* Z1, const float* b3in,
                                                const float* rnn3in, const float* F1, const float* F2,
                                                float* outr, u16* hO) {
    const int base = (blockIdx.x * 256 + threadIdx.x) * 4;
    const int m = base >> 10;
    const float b3f = b3in[2 * m], f1 = F1[m], f2 = F2[m];
    const float4 z0 = *(const float4*)(Z0 + base), z1 = *(const float4*)(Z1 + base);
    const float4 r3 = *(const float4*)(rnn3in + base);
    float4 o;
    o.x = (1.f - f1) * r3.x + f1 * ((1.f - f2) * r3.x + f2 * (b3f * tanhf(z1.x) + (1.f - b3f) * tanhf(z0.x)));
    o.y = (1.f - f1) * r3.y + f1 * ((1.f - f2) * r3.y + f2 * (b3f * tanhf(z1.y) + (1.f - b3f) * tanhf(z0.y)));
    o.z = (1.f - f1) * r3.z + f1 * ((1.f - f2) * r3.z + f2 * (b3f * tanhf(z1.z) + (1.f - b3f) * tanhf(z0.z)));
    o.w = (1.f - f1) * r3.w + f1 * ((1.f - f2) * r3.w + f2 * (b3f * tanhf(z1.w) + (1.f - b3f) * tanhf(z0.w)));
    *(float4*)(outr + base) = o;
    store_hl4(o, hO, nullptr, base);
}
__global__ __launch_bounds__(256) void combine4(const float* Z0, const float* rnn4in, const float* F1,
                                                const float* F2, const float* F3, float* outr, u16* hO) {
    const int base = (blockIdx.x * 256 + threadIdx.x) * 4;
    const int m = base >> 10;
    const float f1 = F1[m], f2 = F2[m], f3 = F3[m];
    const float4 z0 = *(const float4*)(Z0 + base);
    const float4 r4 = *(const float4*)(rnn4in + base);
    float4 o;
    o.x = (1.f - f1) * r4.x + f1 * ((1.f - f2) * r4.x + f2 * ((1.f - f3) * r4.x + f3 * tanhf(z0.x)));
    o.y = (1.f - f1) * r4.y + f1 * ((1.f - f2) * r4.y + f2 * ((1.f - f3) * r4.y + f3 * tanhf(z0.y)));
    o.z = (1.f - f1) * r4.z + f1 * ((1.f - f2) * r4.z + f2 * ((1.f - f3) * r4.z + f3 * tanhf(z0.z)));
    o.w = (1.f - f1) * r4.w + f1 * ((1.f - f2) * r4.w + f2 * ((1.f - f3) * r4.w + f3 * tanhf(z0.w)));
    *(float4*)(outr + base) = o;
    store_hl4(o, hO, nullptr, base);
}

// ---------------- Gumbel-hard decision GEMV (fp32): 1 wave per row ----------------
__global__ __launch_bounds__(256) void gemv_decide(const float* x, const float* W2, const float* bias2,
                                                   const float* gn, const float* bprev,
                                                   const float* Fp1, const float* Fp2,
                                                   float* bout, float* fout, int stage) {
    const int wave = threadIdx.x >> 6, lane = threadIdx.x & 63;
    const int m = blockIdx.x * 4 + wave;
    const float* row = x + (size_t)m * 1024;
    float s0 = 0.f, s1 = 0.f;
#pragma unroll 4
    for (int i = 0; i < 16; i++) {
        const int k = lane + 64 * i;
        const float v = row[k];
        s0 += v * W2[k];
        s1 += v * W2[1024 + k];
    }
    for (int off = 32; off > 0; off >>= 1) { s0 += __shfl_xor(s0, off); s1 += __shfl_xor(s1, off); }
    if (lane == 0) {
        const float l0 = s0 + bias2[0] + gn[2 * m];
        const float l1 = s1 + bias2[1] + gn[2 * m + 1];
        const float nf = (l0 >= l1) ? 1.f : 0.f;
        float v0, v1;
        if (stage == 1) {
            v0 = nf; v1 = 1.f - nf;
        } else if (stage == 2) {
            const float f1 = Fp1[m];
            const float p0 = bprev[2 * m], p1 = bprev[2 * m + 1];
            v0 = f1 * nf + (1.f - f1) * p0;
            v1 = f1 * (1.f - nf) + (1.f - f1) * p1;
        } else {
            const float f1 = Fp1[m], f2 = Fp2[m];
            const float p0 = bprev[2 * m], p1 = bprev[2 * m + 1];
            const float i0 = f2 * nf + (1.f - f2) * p0;
            const float i1 = f2 * (1.f - nf) + (1.f - f2) * p1;
            v0 = f1 * i0 + (1.f - f1) * p0;
            v1 = f1 * i1 + (1.f - f1) * p1;
        }
        fout[m] = v0;
        bout[2 * m] = v0; bout[2 * m + 1] = v1;
    }
}

// ---------------- g = sigmoid(W_g . hg + b): 1 wave per row, 4 outputs ----------------
__global__ __launch_bounds__(256) void gemv_g4(const float* hg, const float* Wg, const float* bg, float* G) {
    const int wave = threadIdx.x >> 6, lane = threadIdx.x & 63;
    const int m = blockIdx.x * 4 + wave;
    const float* row = hg + (size_t)m * 1024;
    float s[4] = {0.f, 0.f, 0.f, 0.f};
#pragma unroll 4
    for (int i = 0; i < 16; i++) {
        const int k = lane + 64 * i;
        const float v = row[k];
#pragma unroll
        for (int j = 0; j < 4; j++) s[j] += v * Wg[j * 1024 + k];
    }
    for (int off = 32; off > 0; off >>= 1)
#pragma unroll
        for (int j = 0; j < 4; j++) s[j] += __shfl_xor(s[j], off);
    if (lane == 0) {
#pragma unroll
        for (int j = 0; j < 4; j++) G[m * 4 + j] = 1.f / (1.f + expf(-(s[j] + bg[j])));
    }
}

// ---------------- gated = concat_j g_j * rnn_jt -> bf16 hi (4096 x 4096) ----------------
__global__ __launch_bounds__(256) void gated_k(const float* rnnF, const float* G, u16* gatedh) {
    const int base = (blockIdx.x * 256 + threadIdx.x) * 4;
    const int m = base >> 12, rem = base & 4095;
    const int j = rem >> 10, k = rem & 1023;
    const float g = G[m * 4 + j];
    const float4 r = *(const float4*)(rnnF + (size_t)j * 4194304 + (size_t)m * 1024 + k);
    u16x4 hv;
    hv[0] = __builtin_bit_cast(u16, (__bf16)(g * r.x));
    hv[1] = __builtin_bit_cast(u16, (__bf16)(g * r.y));
    hv[2] = __builtin_bit_cast(u16, (__bf16)(g * r.z));
    hv[3] = __builtin_bit_cast(u16, (__bf16)(g * r.w));
    *(u16x4*)(gatedh + base) = hv;
}

// ---------------- log_softmax over 256 cols: 1 wave per row, fp32 out ----------------
__global__ __launch_bounds__(256) void logsoftmax_k(const float* Z, float* out) {
    const int wave = threadIdx.x >> 6, lane = threadIdx.x & 63;
    const int row = blockIdx.x * 4 + wave;
    const size_t base = (size_t)row * 256;
    float x[4];
#pragma unroll
    for (int i = 0; i < 4; i++) x[i] = Z[base + lane + 64 * i];
    float mx = fmaxf(fmaxf(x[0], x[1]), fmaxf(x[2], x[3]));
    for (int off = 32; off > 0; off >>= 1) mx = fmaxf(mx, __shfl_xor(mx, off));
    float s = 0.f;
#pragma unroll
    for (int i = 0; i < 4; i++) s += expf(x[i] - mx);
    for (int off = 32; off > 0; off >>= 1) s += __shfl_xor(s, off);
    const float lse = mx + logf(s);
#pragma unroll
    for (int i = 0; i < 4; i++) out[base + lane + 64 * i] = x[i] - lse;
}

// ---------------- host ----------------
static const size_t OUT_B1 = 1048576, OUT_B2 = 1056768, OUT_B3 = 1064960;
static const size_t OUT_R1 = 1073152, OUT_R2 = 5267456, OUT_R3 = 9461760, OUT_R4 = 13656064;

static inline Sec S0(const float* f, int lda) { Sec s; s.h = f; s.l = nullptr; s.lda = lda; s.mode = 0; return s; }
static inline Sec S1(const u16* h, const u16* l, int lda) { Sec s; s.h = h; s.l = l; s.lda = lda; s.mode = 1; return s; }

extern "C" void kernel_launch(void* const* d_in, const int* in_sizes, int n_in,
                              void* d_out, int out_size, void* d_ws, size_t ws_size,
                              hipStream_t stream) {
    (void)in_sizes; (void)n_in; (void)out_size; (void)ws_size;
    const float* ct   = (const float*)d_in[0];
    const float* b1   = (const float*)d_in[1];
    const float* b2   = (const float*)d_in[2];
    const float* b3   = (const float*)d_in[3];
    const float* rnn1 = (const float*)d_in[4];
    const float* rnn2 = (const float*)d_in[5];
    const float* rnn3 = (const float*)d_in[6];
    const float* rnn4 = (const float*)d_in[7];
    const float* gn1  = (const float*)d_in[8];
    const float* gn2  = (const float*)d_in[9];
    const float* gn3  = (const float*)d_in[10];
    const float* W_e    = (const float*)d_in[12]; const float* be    = (const float*)d_in[13];
    const float* W_r1b0 = (const float*)d_in[14]; const float* br1b0 = (const float*)d_in[15];
    const float* W_r1b1 = (const float*)d_in[16]; const float* br1b1 = (const float*)d_in[17];
    const float* W_b1   = (const float*)d_in[18]; const float* bb1   = (const float*)d_in[19];
    const float* W_r2b0 = (const float*)d_in[20]; const float* br2b0 = (const float*)d_in[21];
    const float* W_r2b1 = (const float*)d_in[22]; const float* br2b1 = (const float*)d_in[23];
    const float* W_b2   = (const float*)d_in[24]; const float* bb2   = (const float*)d_in[25];
    const float* W_r3b0 = (const float*)d_in[26]; const float* br3b0 = (const float*)d_in[27];
    const float* W_r3b1 = (const float*)d_in[28]; const float* br3b1 = (const float*)d_in[29];
    const float* W_b3   = (const float*)d_in[30]; const float* bb3   = (const float*)d_in[31];
    const float* W_r4   = (const float*)d_in[32]; const float* br4   = (const float*)d_in[33];
    const float* W_hg   = (const float*)d_in[34]; const float* bhg   = (const float*)d_in[35];
    const float* W_g    = (const float*)d_in[36]; const float* bg    = (const float*)d_in[37];
    const float* W_hct  = (const float*)d_in[38]; const float* bhct  = (const float*)d_in[39];
    const float* W_ct   = (const float*)d_in[40]; const float* bct   = (const float*)d_in[41];

    float* out = (float*)d_out;
    char* w = (char*)d_ws;
    const size_t MB = 1024 * 1024;
    // ws (80MB) lifetime map:
    //  [0,16)  Z0 | HGF | GATEDh(lo half) | ZC
    //  [16,32) Z1 | GATEDh(hi half)
    //  [32,48) weight slab (bf16 h/l, rewritten before each gemm)
    //  [48,56) CTEFh -> R2h -> HCTFh
    //  [56,64) CTEFl -> R2l -> R4h
    //  [64,72) R1h
    //  [72,80) R1l -> R3h
    float* Z0    = (float*)(w);
    float* Z1    = (float*)(w + 16 * MB);
    u16* WS      = (u16*)(w + 32 * MB);
    u16* CTEFh   = (u16*)(w + 48 * MB);
    u16* CTEFl   = (u16*)(w + 56 * MB);
    u16* R1h     = (u16*)(w + 64 * MB);
    u16* R1l     = (u16*)(w + 72 * MB);
    u16* R2h     = (u16*)(w + 48 * MB);
    u16* R2l     = (u16*)(w + 56 * MB);
    u16* R3h     = (u16*)(w + 72 * MB);
    u16* R4h     = (u16*)(w + 56 * MB);
    float* HGF   = (float*)(w);
    u16* GATEDh  = (u16*)(w);
    u16* HCTFh   = (u16*)(w + 48 * MB);
    float* ZC    = (float*)(w);
    float* F1 = out; float* F2 = F1 + 4096; float* F3 = F1 + 8192; float* G4 = F1 + 12288;
    float* R1 = out + OUT_R1; float* R2 = out + OUT_R2;
    float* R3 = out + OUT_R3; float* R4 = out + OUT_R4;

    const int NWe = 32768, NWr = 262144, NWg = 524288, NWct = 32768;  // float8 counts
    auto conv = [&](const float* x0, u16* h0, u16* l0, int n0v,
                    const float* x1, u16* h1, u16* l1, int n1v) {
        const int tot = n0v + n1v;
        conv_split<<<dim3((tot + 255) / 256), 256, 0, stream>>>(x0, h0, l0, n0v, x1, h1, l1, n1v);
    };
    auto launch = [&](const GemmArgs& p, int NT, int npass) {
        if (npass == 3) gemm_v7<3><<<dim3(NT * 32), 256, 0, stream>>>(p);
        else            gemm_v7<1><<<dim3(NT * 32), 256, 0, stream>>>(p);
    };
    const dim3 EW(4096), GV(1024);

    // 1) ct_e = relu(ct @ W_e^T + b) -> CTEF h/l (3-pass, A=ct fp32-mode)
    conv(W_e, WS, WS + 262144, NWe, nullptr, nullptr, nullptr, 0);
    {
        GemmArgs p{};
        p.A0[0] = S0(ct, 256); p.A1[0] = p.A0[0];
        p.B0h = WS; p.B0l = WS + 262144; p.B1h = p.B0h; p.B1l = p.B0l;
        p.bias0 = be; p.bias1 = be;
        p.Zh0 = CTEFh; p.Zl0 = CTEFl; p.Zh1 = CTEFh; p.Zl1 = CTEFl;
        p.bk[0] = 0; p.nsec = 1; p.ldb = 256; p.N = 1024; p.spsl = 3;
        p.relu = 1; p.zmode = 2;
        launch(p, 8, 3);
    }
    // 2) rnn1 dual: Z0=[rnn1,CTE]@Wb0^T, Z1=[rnn2,CTE]@Wb1^T (3-pass)
    conv(W_r1b0, WS, WS + 2097152, NWr, W_r1b1, WS + 4194304, WS + 6291456, NWr);
    {
        GemmArgs p{};
        p.A0[0] = S0(rnn1, 1024); p.A0[1] = S1(CTEFh, CTEFl, 1024);
        p.A1[0] = S0(rnn2, 1024); p.A1[1] = p.A0[1];
        p.B0h = WS; p.B0l = WS + 2097152; p.B1h = WS + 4194304; p.B1l = WS + 6291456;
        p.bias0 = br1b0; p.bias1 = br1b1;
        p.Z0 = Z0; p.Z1 = Z1;
        p.bk[0] = 0; p.bk[1] = 1024; p.nsec = 2; p.ldb = 2048; p.N = 1024; p.spsl = 5;
        p.relu = 0; p.zmode = 0;
        launch(p, 16, 3);
    }
    combine1<<<EW, 256, 0, stream>>>(Z0, Z1, b1, R1, R1h, R1l);
    gemv_decide<<<GV, 256, 0, stream>>>(R1, W_b1, bb1, gn1, b1, F1, F1, out + OUT_B1, F1, 1);
    // 3) rnn2 dual
    conv(W_r2b0, WS, WS + 2097152, NWr, W_r2b1, WS + 4194304, WS + 6291456, NWr);
    {
        GemmArgs p{};
        p.A0[0] = S0(rnn2, 1024); p.A0[1] = S1(R1h, R1l, 1024);
        p.A1[0] = S0(rnn3, 1024); p.A1[1] = p.A0[1];
        p.B0h = WS; p.B0l = WS + 2097152; p.B1h = WS + 4194304; p.B1l = WS + 6291456;
        p.bias0 = br2b0; p.bias1 = br2b1;
        p.Z0 = Z0; p.Z1 = Z1;
        p.bk[0] = 0; p.bk[1] = 1024; p.nsec = 2; p.ldb = 2048; p.N = 1024; p.spsl = 5;
        p.relu = 0; p.zmode = 0;
        launch(p, 16, 3);
    }
    combine2<<<EW, 256, 0, stream>>>(Z0, Z1, b2, rnn2, F1, R2, R2h, R2l);
    gemv_decide<<<GV, 256, 0, stream>>>(R2, W_b2, bb2, gn2, b2, F1, F1, out + OUT_B2, F2, 2);
    // 4) rnn3 dual
    conv(W_r3b0, WS, WS + 2097152, NWr, W_r3b1, WS + 4194304, WS + 6291456, NWr);
    {
        GemmArgs p{};
        p.A0[0] = S0(rnn3, 1024); p.A0[1] = S1(R2h, R2l, 1024);
        p.A1[0] = S0(rnn4, 1024); p.A1[1] = p.A0[1];
        p.B0h = WS; p.B0l = WS + 2097152; p.B1h = WS + 4194304; p.B1l = WS + 6291456;
        p.bias0 = br3b0; p.bias1 = br3b1;
        p.Z0 = Z0; p.Z1 = Z1;
        p.bk[0] = 0; p.bk[1] = 1024; p.nsec = 2; p.ldb = 2048; p.N = 1024; p.spsl = 5;
        p.relu = 0; p.zmode = 0;
        launch(p, 16, 3);
    }
    combine3<<<EW, 256, 0, stream>>>(Z0, Z1, b3, rnn3, F1, F2, R3, R3h);
    gemv_decide<<<GV, 256, 0, stream>>>(R3, W_b3, bb3, gn3, b3, F1, F2, out + OUT_B3, F3, 3);
    // 5) rnn4 (1-pass)
    conv(W_r4, WS, nullptr, NWr, nullptr, nullptr, nullptr, 0);
    {
        GemmArgs p{};
        p.A0[0] = S0(rnn4, 1024); p.A0[1] = S1(R3h, nullptr, 1024);
        p.A1[0] = p.A0[0]; p.A1[1] = p.A0[1];
        p.B0h = WS; p.B0l = nullptr; p.B1h = WS; p.B1l = nullptr;
        p.bias0 = br4; p.bias1 = br4;
        p.Z0 = Z0; p.Z1 = Z0;
        p.bk[0] = 0; p.bk[1] = 1024; p.nsec = 2; p.ldb = 2048; p.N = 1024; p.spsl = 5;
        p.relu = 0; p.zmode = 0;
        launch(p, 8, 1);
    }
    combine4<<<EW, 256, 0, stream>>>(Z0, rnn4, F1, F2, F3, R4, R4h);
    // 6) hg = relu(concat(R1..R4) @ W_hg^T) (1-pass, all pre-split); g
    conv(W_hg, WS, nullptr, NWg, nullptr, nullptr, nullptr, 0);
    {
        GemmArgs p{};
        p.A0[0] = S1(R1h, nullptr, 1024); p.A0[1] = S1(R2h, nullptr, 1024);
        p.A0[2] = S1(R3h, nullptr, 1024); p.A0[3] = S1(R4h, nullptr, 1024);
        p.A1[0] = p.A0[0]; p.A1[1] = p.A0[1]; p.A1[2] = p.A0[2]; p.A1[3] = p.A0[3];
        p.B0h = WS; p.B1h = WS;
        p.bias0 = bhg; p.bias1 = bhg;
        p.Z0 = HGF; p.Z1 = HGF;
        p.bk[0] = 0; p.bk[1] = 1024; p.bk[2] = 2048; p.bk[3] = 3072;
        p.nsec = 4; p.ldb = 4096; p.N = 1024; p.spsl = 5;
        p.relu = 1; p.zmode = 0;
        launch(p, 8, 1);
    }
    gemv_g4<<<GV, 256, 0, stream>>>(HGF, W_g, bg, G4);
    // 7) gated (bf16 hi at ws[0,32)); hctpi (1-pass) -> HCTFh bf16
    gated_k<<<dim3(16384), 256, 0, stream>>>(R1, G4, GATEDh);
    conv(W_hct, WS, nullptr, NWg, nullptr, nullptr, nullptr, 0);
    {
        GemmArgs p{};
        p.A0[0] = S1(GATEDh, nullptr, 4096); p.A1[0] = p.A0[0];
        p.B0h = WS; p.B1h = WS;
        p.bias0 = bhct; p.bias1 = bhct;
        p.Zh0 = HCTFh; p.Zh1 = HCTFh;
        p.bk[0] = 0; p.nsec = 1; p.ldb = 4096; p.N = 1024; p.spsl = 7;
        p.relu = 1; p.zmode = 1;
        launch(p, 8, 1);
    }
    // 8) ctpi = log_softmax(hctpi @ W_ct^T + b)
    conv(W_ct, WS, nullptr, NWct, nullptr, nullptr, nullptr, 0);
    {
        GemmArgs p{};
        p.A0[0] = S1(HCTFh, nullptr, 1024); p.A1[0] = p.A0[0];
        p.B0h = WS; p.B1h = WS;
        p.bias0 = bct; p.bias1 = bct;
        p.Z0 = ZC; p.Z1 = ZC;
        p.bk[0] = 0; p.nsec = 1; p.ldb = 1024; p.N = 256; p.spsl = 5;
        p.relu = 0; p.zmode = 0;
        launch(p, 4, 1);
    }
    logsoftmax_k<<<GV, 256, 0, stream>>>(ZC, out);
}

// Round 7
// 882.813 us; speedup vs baseline: 1.1751x; 1.1751x over previous
//
#include <hip/hip_runtime.h>
#include <cstdint>
#include <cstddef>

typedef unsigned short u16;
typedef __bf16 bf16x8 __attribute__((ext_vector_type(8)));
typedef float  f32x4  __attribute__((ext_vector_type(4)));
typedef u16    u16x4  __attribute__((ext_vector_type(4)));

__device__ __forceinline__ void splitv(const float4 a, const float4 b, bf16x8& h, bf16x8& l) {
    float x[8] = {a.x, a.y, a.z, a.w, b.x, b.y, b.z, b.w};
#pragma unroll
    for (int i = 0; i < 8; i++) {
        __bf16 hh = (__bf16)x[i];
        h[i] = hh;
        l[i] = (__bf16)(x[i] - (float)hh);   // exact residual in fp32
    }
}
__device__ __forceinline__ void hiv(const float4 a, const float4 b, bf16x8& h) {
    float x[8] = {a.x, a.y, a.z, a.w, b.x, b.y, b.z, b.w};
#pragma unroll
    for (int i = 0; i < 8; i++) h[i] = (__bf16)x[i];
}

// async global->LDS, 16B per lane. LDS dest = wave-uniform base + lane*16.
__device__ __forceinline__ void gl16(const void* g, void* l) {
    __builtin_amdgcn_global_load_lds((__attribute__((address_space(1))) void*)g,
                                     (__attribute__((address_space(3))) void*)l, 16, 0, 0);
}

// Section modes: mode==0 -> fp32 source, in-kernel split (raw inputs, first use only);
//                mode==1 -> pre-split bf16 h (+l for NP==3), staged via global_load_lds.
struct Sec {
    const void* h;   // fp32 base (mode 0) or bf16-hi base (mode 1)
    const u16*  l;   // bf16-lo base (mode 1, NP==3)
    int lda; int mode;
};
struct GemmArgs {
    Sec A0[4]; Sec A1[4];                  // per-half A sections
    const u16* B0h; const u16* B0l;        // pre-split weights per half
    const u16* B1h; const u16* B1l;
    const float* bias0; const float* bias1;
    float* Z0; float* Z1;                  // fp32 out (zmode 0)
    u16* Zh0; u16* Zl0; u16* Zh1; u16* Zl1;// bf16 out (zmode 1: h, zmode 2: h+l)
    int bk[4];                             // per-section K offset into B rows
    int nsec, ldb, N, spsl, relu, zmode;
};

// ---- GEMM v8 ----
// NP3 path: EXACTLY v6 (best measured: duals 127us): tile 128x128, 4 waves of 64x64,
//   BK=32, dbuf, one __syncthreads per K-step. No asm/sched directives (v4/v5/v7 all
//   showed pinning is neutral-to-negative here).
// NP1 path (rnn4/hg/hct/ctpi were 1 block/CU = 1 wave/SIMD, latency-exposed):
//   tile 128x64, 4 waves of 64x32, G=2 K-substeps per barrier, dbuf 48KB.
//   -> grid doubles (NT=N/64): 2 blocks/CU = 2 waves/SIMD, and barrier-steps halve
//   with 2x MFMA cover each. Same staging primitives/swizzle; numerics identical.
// grid = NT_total*32 flat; swizzle: XCD k (bid%8) owns mtiles [4k,4k+4) for all ntiles.
// LDS slot swizzle: stored slot = logical slot ^ ((row ^ row>>2)&3), both sides.
template <int NP>
__global__ __launch_bounds__(256, 2) void gemm_v8(GemmArgs p) {
    constexpr bool NP3 = (NP == 3);
    constexpr int G  = NP3 ? 1 : 2;         // K-substeps per barrier step
    constexpr int BN = NP3 ? 128 : 64;      // N tile
    constexpr int NJ = NP3 ? 4 : 2;         // B-frags per wave
    constexpr int BROWS = BN;               // B tile rows per substep
    __shared__ __align__(16) u16 AhS[2][G][4096];        // 128 x 32 per substep
    __shared__ __align__(16) u16 BhS[2][G][BROWS * 32];  // BN x 32 per substep
    __shared__ __align__(16) u16 AlS[NP3 ? 2 : 1][NP3 ? 4096 : 8];
    __shared__ __align__(16) u16 BlS[NP3 ? 2 : 1][NP3 ? 4096 : 8];

    const int tid = threadIdx.x;
    const int lin = blockIdx.x;
    const int mt = ((lin & 7) << 2) | ((lin >> 3) & 3);
    const int nt = lin >> 5;
    const int NTh = p.N / BN;
    const int half = (nt >= NTh) ? 1 : 0;
    const int n0 = (nt - (half ? NTh : 0)) * BN;
    const int m0 = mt * 128;
    const u16* Bwh = half ? p.B1h : p.B0h;
    const u16* Bwl = half ? p.B1l : p.B0l;
    const float* bia = half ? p.bias1 : p.bias0;
    float* Z = half ? p.Z1 : p.Z0;
    u16* Zh = half ? p.Zh1 : p.Zh0;
    u16* Zl = half ? p.Zl1 : p.Zl0;
    const Sec* As = half ? p.A1 : p.A0;

    const int wave = tid >> 6, lane = tid & 63;
    const int quad = lane >> 4, lr = lane & 15;
    const int wm = (wave & 1) * 64;
    const int wn = (wave >> 1) * (NP3 ? 64 : 32);

    f32x4 acc[4][NJ];
#pragma unroll
    for (int i = 0; i < 4; i++)
#pragma unroll
        for (int j = 0; j < NJ; j++) acc[i][j] = (f32x4){0.f, 0.f, 0.f, 0.f};

    // staging geometry: thread covers rows arow(/arow+64), slot aslot (16B slots, 64B rows)
    const int arow = tid >> 2;                              // 0..63
    const int aslot = tid & 3;
    const int csw = aslot ^ ((arow ^ (arow >> 2)) & 3);     // swizzled slot (same for row+64)
    const int wr_i0 = arow * 32 + csw * 8;                  // u16 index for fp32-mode LDS write
    const int ldsw = wave * 1024;                           // wave-uniform byte base for gl16
    // read-side swizzle: logical slot = quad; row term = (lr ^ lr>>2)&3 (valid for wn mult 32)
    const int qx8 = ((quad ^ ((lr ^ (lr >> 2)) & 3)) & 3) * 8;

    const int sps = 1 << p.spsl;
    const int total = p.nsec << p.spsl;     // BK=32 substeps
    const int ng = total / G;               // barrier steps

    float4 v[G][4];
#pragma unroll
    for (int k = 0; k < G; k++)
#pragma unroll
        for (int q = 0; q < 4; q++) v[k][q] = (float4){0.f, 0.f, 0.f, 0.f};

    auto regload = [&](int k, const Sec& sec, int t) {
        const float* a0 = (const float*)sec.h + (size_t)(m0 + arow) * sec.lda + t * 32 + aslot * 8;
        v[k][0] = ((const float4*)a0)[0]; v[k][1] = ((const float4*)a0)[1];
        const float* a1 = a0 + (size_t)64 * sec.lda;
        v[k][2] = ((const float4*)a1)[0]; v[k][3] = ((const float4*)a1)[1];
    };
    auto writeA0 = [&](int buf, int k) {
        if constexpr (NP3) {
            bf16x8 h, l;
            splitv(v[k][0], v[k][1], h, l);
            *(bf16x8*)&AhS[buf][0][wr_i0] = h;        *(bf16x8*)&AlS[buf][wr_i0] = l;
            splitv(v[k][2], v[k][3], h, l);
            *(bf16x8*)&AhS[buf][0][2048 + wr_i0] = h; *(bf16x8*)&AlS[buf][2048 + wr_i0] = l;
        } else {
            bf16x8 h;
            hiv(v[k][0], v[k][1], h); *(bf16x8*)&AhS[buf][k][wr_i0] = h;
            hiv(v[k][2], v[k][3], h); *(bf16x8*)&AhS[buf][k][2048 + wr_i0] = h;
        }
    };
    auto stageA1 = [&](int buf, int k, const Sec& sec, int t) {
        const u16* gh = (const u16*)sec.h;
        const size_t o0 = (size_t)(m0 + arow) * sec.lda + t * 32 + csw * 8;
        const size_t o1 = o0 + (size_t)64 * sec.lda;
        gl16(gh + o0, (char*)&AhS[buf][k][0] + ldsw);
        gl16(gh + o1, (char*)&AhS[buf][k][0] + 4096 + ldsw);
        if constexpr (NP3) {
            gl16(sec.l + o0, (char*)&AlS[buf][0] + ldsw);
            gl16(sec.l + o1, (char*)&AlS[buf][0] + 4096 + ldsw);
        }
    };
    auto stageB = [&](int buf, int k, int s, int t) {
        const size_t o0 = (size_t)(n0 + arow) * p.ldb + p.bk[s] + t * 32 + csw * 8;
        gl16(Bwh + o0, (char*)&BhS[buf][k][0] + ldsw);
        if constexpr (NP3) {
            const size_t o1 = o0 + (size_t)64 * p.ldb;
            gl16(Bwh + o1, (char*)&BhS[buf][k][0] + 4096 + ldsw);
            gl16(Bwl + o0, (char*)&BlS[buf][0] + ldsw);
            gl16(Bwl + o1, (char*)&BlS[buf][0] + 4096 + ldsw);
        }
    };

    // ---- prologue: fill buf0 with group 0; prefetch regs for group 1 (fp32 sections) ----
#pragma unroll
    for (int k = 0; k < G; k++) {
        stageB(0, k, 0, k);
        const Sec s0 = As[0];
        if (s0.mode == 0) { regload(k, s0, k); writeA0(0, k); }
        else stageA1(0, k, s0, k);
    }
#pragma unroll
    for (int k = 0; k < G; k++) {
        const int u = G + k;
        if (u < total) {
            const Sec s1 = As[u >> p.spsl];
            if (s1.mode == 0) regload(k, s1, u & (sps - 1));
        }
    }
    __syncthreads();

    for (int gg = 0; gg < ng; ++gg) {
        const int cur = gg & 1, nxt = cur ^ 1;
        // ---- stage group gg+1 into buf[nxt] FIRST (latency covered by compute below) ----
        if (gg + 1 < ng) {
#pragma unroll
            for (int k = 0; k < G; k++) {
                const int u = (gg + 1) * G + k, s = u >> p.spsl, t = u & (sps - 1);
                stageB(nxt, k, s, t);
                const Sec sec = As[s];
                if (sec.mode == 0) writeA0(nxt, k);   // v[k] holds group gg+1 data
                else stageA1(nxt, k, sec, t);
            }
#pragma unroll
            for (int k = 0; k < G; k++) {
                const int u2 = (gg + 2) * G + k;
                if (u2 < total) {
                    const Sec sec2 = As[u2 >> p.spsl];
                    if (sec2.mode == 0) regload(k, sec2, u2 & (sps - 1));
                }
            }
        }
        // ---- compute group gg from buf[cur] ----
#pragma unroll
        for (int k = 0; k < G; k++) {
            bf16x8 ah[4], bh[NJ];
#pragma unroll
            for (int i = 0; i < 4; i++)
                ah[i] = *reinterpret_cast<const bf16x8*>(&AhS[cur][k][(wm + i * 16 + lr) * 32 + qx8]);
#pragma unroll
            for (int j = 0; j < NJ; j++)
                bh[j] = *reinterpret_cast<const bf16x8*>(&BhS[cur][k][(wn + j * 16 + lr) * 32 + qx8]);
#pragma unroll
            for (int i = 0; i < 4; i++)
#pragma unroll
                for (int j = 0; j < NJ; j++)
                    acc[i][j] = __builtin_amdgcn_mfma_f32_16x16x32_bf16(ah[i], bh[j], acc[i][j], 0, 0, 0);
            if constexpr (NP3) {
                bf16x8 al[4], bl[NJ];
#pragma unroll
                for (int i = 0; i < 4; i++)
                    al[i] = *reinterpret_cast<const bf16x8*>(&AlS[cur][(wm + i * 16 + lr) * 32 + qx8]);
#pragma unroll
                for (int j = 0; j < NJ; j++)
                    bl[j] = *reinterpret_cast<const bf16x8*>(&BlS[cur][(wn + j * 16 + lr) * 32 + qx8]);
#pragma unroll
                for (int i = 0; i < 4; i++)
#pragma unroll
                    for (int j = 0; j < NJ; j++) {
                        acc[i][j] = __builtin_amdgcn_mfma_f32_16x16x32_bf16(ah[i], bl[j], acc[i][j], 0, 0, 0);
                        acc[i][j] = __builtin_amdgcn_mfma_f32_16x16x32_bf16(al[i], bh[j], acc[i][j], 0, 0, 0);
                    }
            }
        }
        // one barrier per step: my staging for buf[nxt] drains here (latency covered by
        // the compute above); everyone's buf[cur] reads done before next overwrite.
        __syncthreads();
    }

#pragma unroll
    for (int j = 0; j < NJ; j++) {
        const int n = n0 + wn + j * 16 + lr;                 // C/D col = lane&15
        const float bj = bia[n];
#pragma unroll
        for (int i = 0; i < 4; i++)
#pragma unroll
            for (int r = 0; r < 4; r++) {
                const int m = m0 + wm + i * 16 + quad * 4 + r;  // C/D row = quad*4+reg
                float v2 = acc[i][j][r] + bj;
                if (p.relu) v2 = fmaxf(v2, 0.f);
                const size_t zi = (size_t)m * p.N + n;
                if (p.zmode == 0) {
                    Z[zi] = v2;
                } else {
                    __bf16 hb = (__bf16)v2;
                    Zh[zi] = __builtin_bit_cast(u16, hb);
                    if (p.zmode == 2)
                        Zl[zi] = __builtin_bit_cast(u16, (__bf16)(v2 - (float)hb));
                }
            }
    }
}

// ---------------- fp32 -> bf16 hi(/lo) conversion (weights), 2 sources per launch ----------------
__global__ __launch_bounds__(256) void conv_split(const float* x0, u16* h0, u16* l0, int n0v,
                                                  const float* x1, u16* h1, u16* l1, int n1v) {
    int i = blockIdx.x * 256 + threadIdx.x;
    const float* x; u16* h; u16* l;
    if (i < n0v) { x = x0; h = h0; l = l0; }
    else { i -= n0v; if (i >= n1v) return; x = x1; h = h1; l = l1; }
    const float4 a = ((const float4*)x)[2 * i], b = ((const float4*)x)[2 * i + 1];
    bf16x8 hh, ll;
    if (l) { splitv(a, b, hh, ll); ((bf16x8*)h)[i] = hh; ((bf16x8*)l)[i] = ll; }
    else   { hiv(a, b, hh);        ((bf16x8*)h)[i] = hh; }
}

__device__ __forceinline__ void store_hl4(const float4 o, u16* hp, u16* lp, int base) {
    float xs[4] = {o.x, o.y, o.z, o.w};
    u16x4 hv, lv;
#pragma unroll
    for (int k = 0; k < 4; k++) {
        __bf16 hb = (__bf16)xs[k];
        hv[k] = __builtin_bit_cast(u16, hb);
        if (lp) lv[k] = __builtin_bit_cast(u16, (__bf16)(xs[k] - (float)hb));
    }
    *(u16x4*)(hp + base) = hv;
    if (lp) *(u16x4*)(lp + base) = lv;
}

// ---------------- elementwise combines (4096x1024): fp32 out + pre-split bf16 out ----------------
__global__ __launch_bounds__(256) void combine1(const float* Z0, const float* Z1, const float* b1in,
                                                float* outr, u16* hO, u16* lO) {
    const int base = (blockIdx.x * 256 + threadIdx.x) * 4;
    const int m = base >> 10;
    const float bf = b1in[2 * m];
    const float4 z0 = *(const float4*)(Z0 + base), z1 = *(const float4*)(Z1 + base);
    float4 o;
    o.x = bf * tanhf(z1.x) + (1.f - bf) * tanhf(z0.x);
    o.y = bf * tanhf(z1.y) + (1.f - bf) * tanhf(z0.y);
    o.z = bf * tanhf(z1.z) + (1.f - bf) * tanhf(z0.z);
    o.w = bf * tanhf(z1.w) + (1.f - bf) * tanhf(z0.w);
    *(float4*)(outr + base) = o;
    store_hl4(o, hO, lO, base);
}
__global__ __launch_bounds__(256) void combine2(const float* Z0, const float* Z1, const float* b2in,
                                                const float* rnn2in, const float* F1, float* outr,
                                                u16* hO, u16* lO) {
    const int base = (blockIdx.x * 256 + threadIdx.x) * 4;
    const int m = base >> 10;
    const float b2f = b2in[2 * m], f1 = F1[m];
    const float4 z0 = *(const float4*)(Z0 + base), z1 = *(const float4*)(Z1 + base);
    const float4 r2 = *(const float4*)(rnn2in + base);
    float4 o;
    o.x = (1.f - f1) * r2.x + f1 * ((1.f - b2f) * tanhf(z0.x) + b2f * tanhf(z1.x));
    o.y = (1.f - f1) * r2.y + f1 * ((1.f - b2f) * tanhf(z0.y) + b2f * tanhf(z1.y));
    o.z = (1.f - f1) * r2.z + f1 * ((1.f - b2f) * tanhf(z0.z) + b2f * tanhf(z1.z));
    o.w = (1.f - f1) * r2.w + f1 * ((1.f - b2f) * tanhf(z0.w) + b2f * tanhf(z1.w));
    *(float4*)(outr + base) = o;
    store_hl4(o, hO, lO, base);
}
__global__ __launch_bounds__(256) void combine3(const float* Z0, const float* Z1, const float* b3in,
                                                const float* rnn3in, const float* F1, const float* F2,
                                                float* outr, u16* hO) {
    const int base = (blockIdx.x * 256 + threadIdx.x) * 4;
    const int m = base >> 10;
    const float b3f = b3in[2 * m], f1 = F1[m], f2 = F2[m];
    const float4 z0 = *(const float4*)(Z0 + base), z1 = *(const float4*)(Z1 + base);
    const float4 r3 = *(const float4*)(rnn3in + base);
    float4 o;
    o.x = (1.f - f1) * r3.x + f1 * ((1.f - f2) * r3.x + f2 * (b3f * tanhf(z1.x) + (1.f - b3f) * tanhf(z0.x)));
    o.y = (1.f - f1) * r3.y + f1 * ((1.f - f2) * r3.y + f2 * (b3f * tanhf(z1.y) + (1.f - b3f) * tanhf(z0.y)));
    o.z = (1.f - f1) * r3.z + f1 * ((1.f - f2) * r3.z + f2 * (b3f * tanhf(z1.z) + (1.f - b3f) * tanhf(z0.z)));
    o.w = (1.f - f1) * r3.w + f1 * ((1.f - f2) * r3.w + f2 * (b3f * tanhf(z1.w) + (1.f - b3f) * tanhf(z0.w)));
    *(float4*)(outr + base) = o;
    store_hl4(o, hO, nullptr, base);
}
__global__ __launch_bounds__(256) void combine4(const float* Z0, const float* rnn4in, const float* F1,
                                                const float* F2, const float* F3, float* outr, u16* hO) {
    const int base = (blockIdx.x * 256 + threadIdx.x) * 4;
    const int m = base >> 10;
    const float f1 = F1[m], f2 = F2[m], f3 = F3[m];
    const float4 z0 = *(const float4*)(Z0 + base);
    const float4 r4 = *(const float4*)(rnn4in + base);
    float4 o;
    o.x = (1.f - f1) * r4.x + f1 * ((1.f - f2) * r4.x + f2 * ((1.f - f3) * r4.x + f3 * tanhf(z0.x)));
    o.y = (1.f - f1) * r4.y + f1 * ((1.f - f2) * r4.y + f2 * ((1.f - f3) * r4.y + f3 * tanhf(z0.y)));
    o.z = (1.f - f1) * r4.z + f1 * ((1.f - f2) * r4.z + f2 * ((1.f - f3) * r4.z + f3 * tanhf(z0.z)));
    o.w = (1.f - f1) * r4.w + f1 * ((1.f - f2) * r4.w + f2 * ((1.f - f3) * r4.w + f3 * tanhf(z0.w)));
    *(float4*)(outr + base) = o;
    store_hl4(o, hO, nullptr, base);
}

// ---------------- Gumbel-hard decision GEMV (fp32): 1 wave per row ----------------
__global__ __launch_bounds__(256) void gemv_decide(const float* x, const float* W2, const float* bias2,
                                                   const float* gn, const float* bprev,
                                                   const float* Fp1, const float* Fp2,
                                                   float* bout, float* fout, int stage) {
    const int wave = threadIdx.x >> 6, lane = threadIdx.x & 63;
    const int m = blockIdx.x * 4 + wave;
    const float* row = x + (size_t)m * 1024;
    float s0 = 0.f, s1 = 0.f;
#pragma unroll 4
    for (int i = 0; i < 16; i++) {
        const int k = lane + 64 * i;
        const float v = row[k];
        s0 += v * W2[k];
        s1 += v * W2[1024 + k];
    }
    for (int off = 32; off > 0; off >>= 1) { s0 += __shfl_xor(s0, off); s1 += __shfl_xor(s1, off); }
    if (lane == 0) {
        const float l0 = s0 + bias2[0] + gn[2 * m];
        const float l1 = s1 + bias2[1] + gn[2 * m + 1];
        const float nf = (l0 >= l1) ? 1.f : 0.f;
        float v0, v1;
        if (stage == 1) {
            v0 = nf; v1 = 1.f - nf;
        } else if (stage == 2) {
            const float f1 = Fp1[m];
            const float p0 = bprev[2 * m], p1 = bprev[2 * m + 1];
            v0 = f1 * nf + (1.f - f1) * p0;
            v1 = f1 * (1.f - nf) + (1.f - f1) * p1;
        } else {
            const float f1 = Fp1[m], f2 = Fp2[m];
            const float p0 = bprev[2 * m], p1 = bprev[2 * m + 1];
            const float i0 = f2 * nf + (1.f - f2) * p0;
            const float i1 = f2 * (1.f - nf) + (1.f - f2) * p1;
            v0 = f1 * i0 + (1.f - f1) * p0;
            v1 = f1 * i1 + (1.f - f1) * p1;
        }
        fout[m] = v0;
        bout[2 * m] = v0; bout[2 * m + 1] = v1;
    }
}

// ---------------- g = sigmoid(W_g . hg + b): 1 wave per row, 4 outputs ----------------
__global__ __launch_bounds__(256) void gemv_g4(const float* hg, const float* Wg, const float* bg, float* G) {
    const int wave = threadIdx.x >> 6, lane = threadIdx.x & 63;
    const int m = blockIdx.x * 4 + wave;
    const float* row = hg + (size_t)m * 1024;
    float s[4] = {0.f, 0.f, 0.f, 0.f};
#pragma unroll 4
    for (int i = 0; i < 16; i++) {
        const int k = lane + 64 * i;
        const float v = row[k];
#pragma unroll
        for (int j = 0; j < 4; j++) s[j] += v * Wg[j * 1024 + k];
    }
    for (int off = 32; off > 0; off >>= 1)
#pragma unroll
        for (int j = 0; j < 4; j++) s[j] += __shfl_xor(s[j], off);
    if (lane == 0) {
#pragma unroll
        for (int j = 0; j < 4; j++) G[m * 4 + j] = 1.f / (1.f + expf(-(s[j] + bg[j])));
    }
}

// ---------------- gated = concat_j g_j * rnn_jt -> bf16 hi (4096 x 4096) ----------------
__global__ __launch_bounds__(256) void gated_k(const float* rnnF, const float* G, u16* gatedh) {
    const int base = (blockIdx.x * 256 + threadIdx.x) * 4;
    const int m = base >> 12, rem = base & 4095;
    const int j = rem >> 10, k = rem & 1023;
    const float g = G[m * 4 + j];
    const float4 r = *(const float4*)(rnnF + (size_t)j * 4194304 + (size_t)m * 1024 + k);
    u16x4 hv;
    hv[0] = __builtin_bit_cast(u16, (__bf16)(g * r.x));
    hv[1] = __builtin_bit_cast(u16, (__bf16)(g * r.y));
    hv[2] = __builtin_bit_cast(u16, (__bf16)(g * r.z));
    hv[3] = __builtin_bit_cast(u16, (__bf16)(g * r.w));
    *(u16x4*)(gatedh + base) = hv;
}

// ---------------- log_softmax over 256 cols: 1 wave per row, fp32 out ----------------
__global__ __launch_bounds__(256) void logsoftmax_k(const float* Z, float* out) {
    const int wave = threadIdx.x >> 6, lane = threadIdx.x & 63;
    const int row = blockIdx.x * 4 + wave;
    const size_t base = (size_t)row * 256;
    float x[4];
#pragma unroll
    for (int i = 0; i < 4; i++) x[i] = Z[base + lane + 64 * i];
    float mx = fmaxf(fmaxf(x[0], x[1]), fmaxf(x[2], x[3]));
    for (int off = 32; off > 0; off >>= 1) mx = fmaxf(mx, __shfl_xor(mx, off));
    float s = 0.f;
#pragma unroll
    for (int i = 0; i < 4; i++) s += expf(x[i] - mx);
    for (int off = 32; off > 0; off >>= 1) s += __shfl_xor(s, off);
    const float lse = mx + logf(s);
#pragma unroll
    for (int i = 0; i < 4; i++) out[base + lane + 64 * i] = x[i] - lse;
}

// ---------------- host ----------------
static const size_t OUT_B1 = 1048576, OUT_B2 = 1056768, OUT_B3 = 1064960;
static const size_t OUT_R1 = 1073152, OUT_R2 = 5267456, OUT_R3 = 9461760, OUT_R4 = 13656064;

static inline Sec S0(const float* f, int lda) { Sec s; s.h = f; s.l = nullptr; s.lda = lda; s.mode = 0; return s; }
static inline Sec S1(const u16* h, const u16* l, int lda) { Sec s; s.h = h; s.l = l; s.lda = lda; s.mode = 1; return s; }

extern "C" void kernel_launch(void* const* d_in, const int* in_sizes, int n_in,
                              void* d_out, int out_size, void* d_ws, size_t ws_size,
                              hipStream_t stream) {
    (void)in_sizes; (void)n_in; (void)out_size; (void)ws_size;
    const float* ct   = (const float*)d_in[0];
    const float* b1   = (const float*)d_in[1];
    const float* b2   = (const float*)d_in[2];
    const float* b3   = (const float*)d_in[3];
    const float* rnn1 = (const float*)d_in[4];
    const float* rnn2 = (const float*)d_in[5];
    const float* rnn3 = (const float*)d_in[6];
    const float* rnn4 = (const float*)d_in[7];
    const float* gn1  = (const float*)d_in[8];
    const float* gn2  = (const float*)d_in[9];
    const float* gn3  = (const float*)d_in[10];
    const float* W_e    = (const float*)d_in[12]; const float* be    = (const float*)d_in[13];
    const float* W_r1b0 = (const float*)d_in[14]; const float* br1b0 = (const float*)d_in[15];
    const float* W_r1b1 = (const float*)d_in[16]; const float* br1b1 = (const float*)d_in[17];
    const float* W_b1   = (const float*)d_in[18]; const float* bb1   = (const float*)d_in[19];
    const float* W_r2b0 = (const float*)d_in[20]; const float* br2b0 = (const float*)d_in[21];
    const float* W_r2b1 = (const float*)d_in[22]; const float* br2b1 = (const float*)d_in[23];
    const float* W_b2   = (const float*)d_in[24]; const float* bb2   = (const float*)d_in[25];
    const float* W_r3b0 = (const float*)d_in[26]; const float* br3b0 = (const float*)d_in[27];
    const float* W_r3b1 = (const float*)d_in[28]; const float* br3b1 = (const float*)d_in[29];
    const float* W_b3   = (const float*)d_in[30]; const float* bb3   = (const float*)d_in[31];
    const float* W_r4   = (const float*)d_in[32]; const float* br4   = (const float*)d_in[33];
    const float* W_hg   = (const float*)d_in[34]; const float* bhg   = (const float*)d_in[35];
    const float* W_g    = (const float*)d_in[36]; const float* bg    = (const float*)d_in[37];
    const float* W_hct  = (const float*)d_in[38]; const float* bhct  = (const float*)d_in[39];
    const float* W_ct   = (const float*)d_in[40]; const float* bct   = (const float*)d_in[41];

    float* out = (float*)d_out;
    char* w = (char*)d_ws;
    const size_t MB = 1024 * 1024;
    // ws (80MB) lifetime map:
    //  [0,16)  Z0 | HGF | GATEDh(lo half) | ZC
    //  [16,32) Z1 | GATEDh(hi half)
    //  [32,48) weight slab (bf16 h/l, rewritten before each gemm)
    //  [48,56) CTEFh -> R2h -> HCTFh
    //  [56,64) CTEFl -> R2l -> R4h
    //  [64,72) R1h
    //  [72,80) R1l -> R3h
    float* Z0    = (float*)(w);
    float* Z1    = (float*)(w + 16 * MB);
    u16* WS      = (u16*)(w + 32 * MB);
    u16* CTEFh   = (u16*)(w + 48 * MB);
    u16* CTEFl   = (u16*)(w + 56 * MB);
    u16* R1h     = (u16*)(w + 64 * MB);
    u16* R1l     = (u16*)(w + 72 * MB);
    u16* R2h     = (u16*)(w + 48 * MB);
    u16* R2l     = (u16*)(w + 56 * MB);
    u16* R3h     = (u16*)(w + 72 * MB);
    u16* R4h     = (u16*)(w + 56 * MB);
    float* HGF   = (float*)(w);
    u16* GATEDh  = (u16*)(w);
    u16* HCTFh   = (u16*)(w + 48 * MB);
    float* ZC    = (float*)(w);
    float* F1 = out; float* F2 = F1 + 4096; float* F3 = F1 + 8192; float* G4 = F1 + 12288;
    float* R1 = out + OUT_R1; float* R2 = out + OUT_R2;
    float* R3 = out + OUT_R3; float* R4 = out + OUT_R4;

    const int NWe = 32768, NWr = 262144, NWg = 524288, NWct = 32768;  // float8 counts
    auto conv = [&](const float* x0, u16* h0, u16* l0, int n0v,
                    const float* x1, u16* h1, u16* l1, int n1v) {
        const int tot = n0v + n1v;
        conv_split<<<dim3((tot + 255) / 256), 256, 0, stream>>>(x0, h0, l0, n0v, x1, h1, l1, n1v);
    };
    auto launch = [&](const GemmArgs& p, int NT, int npass) {
        if (npass == 3) gemm_v8<3><<<dim3(NT * 32), 256, 0, stream>>>(p);
        else            gemm_v8<1><<<dim3(NT * 32), 256, 0, stream>>>(p);
    };
    const dim3 EW(4096), GV(1024);

    // 1) ct_e = relu(ct @ W_e^T + b) -> CTEF h/l (3-pass, A=ct fp32-mode)
    conv(W_e, WS, WS + 262144, NWe, nullptr, nullptr, nullptr, 0);
    {
        GemmArgs p{};
        p.A0[0] = S0(ct, 256); p.A1[0] = p.A0[0];
        p.B0h = WS; p.B0l = WS + 262144; p.B1h = p.B0h; p.B1l = p.B0l;
        p.bias0 = be; p.bias1 = be;
        p.Zh0 = CTEFh; p.Zl0 = CTEFl; p.Zh1 = CTEFh; p.Zl1 = CTEFl;
        p.bk[0] = 0; p.nsec = 1; p.ldb = 256; p.N = 1024; p.spsl = 3;
        p.relu = 1; p.zmode = 2;
        launch(p, 8, 3);
    }
    // 2) rnn1 dual: Z0=[rnn1,CTE]@Wb0^T, Z1=[rnn2,CTE]@Wb1^T (3-pass, NP3 = v6 path)
    conv(W_r1b0, WS, WS + 2097152, NWr, W_r1b1, WS + 4194304, WS + 6291456, NWr);
    {
        GemmArgs p{};
        p.A0[0] = S0(rnn1, 1024); p.A0[1] = S1(CTEFh, CTEFl, 1024);
        p.A1[0] = S0(rnn2, 1024); p.A1[1] = p.A0[1];
        p.B0h = WS; p.B0l = WS + 2097152; p.B1h = WS + 4194304; p.B1l = WS + 6291456;
        p.bias0 = br1b0; p.bias1 = br1b1;
        p.Z0 = Z0; p.Z1 = Z1;
        p.bk[0] = 0; p.bk[1] = 1024; p.nsec = 2; p.ldb = 2048; p.N = 1024; p.spsl = 5;
        p.relu = 0; p.zmode = 0;
        launch(p, 16, 3);
    }
    combine1<<<EW, 256, 0, stream>>>(Z0, Z1, b1, R1, R1h, R1l);
    gemv_decide<<<GV, 256, 0, stream>>>(R1, W_b1, bb1, gn1, b1, F1, F1, out + OUT_B1, F1, 1);
    // 3) rnn2 dual
    conv(W_r2b0, WS, WS + 2097152, NWr, W_r2b1, WS + 4194304, WS + 6291456, NWr);
    {
        GemmArgs p{};
        p.A0[0] = S0(rnn2, 1024); p.A0[1] = S1(R1h, R1l, 1024);
        p.A1[0] = S0(rnn3, 1024); p.A1[1] = p.A0[1];
        p.B0h = WS; p.B0l = WS + 2097152; p.B1h = WS + 4194304; p.B1l = WS + 6291456;
        p.bias0 = br2b0; p.bias1 = br2b1;
        p.Z0 = Z0; p.Z1 = Z1;
        p.bk[0] = 0; p.bk[1] = 1024; p.nsec = 2; p.ldb = 2048; p.N = 1024; p.spsl = 5;
        p.relu = 0; p.zmode = 0;
        launch(p, 16, 3);
    }
    combine2<<<EW, 256, 0, stream>>>(Z0, Z1, b2, rnn2, F1, R2, R2h, R2l);
    gemv_decide<<<GV, 256, 0, stream>>>(R2, W_b2, bb2, gn2, b2, F1, F1, out + OUT_B2, F2, 2);
    // 4) rnn3 dual
    conv(W_r3b0, WS, WS + 2097152, NWr, W_r3b1, WS + 4194304, WS + 6291456, NWr);
    {
        GemmArgs p{};
        p.A0[0] = S0(rnn3, 1024); p.A0[1] = S1(R2h, R2l, 1024);
        p.A1[0] = S0(rnn4, 1024); p.A1[1] = p.A0[1];
        p.B0h = WS; p.B0l = WS + 2097152; p.B1h = WS + 4194304; p.B1l = WS + 6291456;
        p.bias0 = br3b0; p.bias1 = br3b1;
        p.Z0 = Z0; p.Z1 = Z1;
        p.bk[0] = 0; p.bk[1] = 1024; p.nsec = 2; p.ldb = 2048; p.N = 1024; p.spsl = 5;
        p.relu = 0; p.zmode = 0;
        launch(p, 16, 3);
    }
    combine3<<<EW, 256, 0, stream>>>(Z0, Z1, b3, rnn3, F1, F2, R3, R3h);
    gemv_decide<<<GV, 256, 0, stream>>>(R3, W_b3, bb3, gn3, b3, F1, F2, out + OUT_B3, F3, 3);
    // 5) rnn4 (1-pass, NP1: 128x64 tiles, grid 512 = 2 blocks/CU)
    conv(W_r4, WS, nullptr, NWr, nullptr, nullptr, nullptr, 0);
    {
        GemmArgs p{};
        p.A0[0] = S0(rnn4, 1024); p.A0[1] = S1(R3h, nullptr, 1024);
        p.A1[0] = p.A0[0]; p.A1[1] = p.A0[1];
        p.B0h = WS; p.B0l = nullptr; p.B1h = WS; p.B1l = nullptr;
        p.bias0 = br4; p.bias1 = br4;
        p.Z0 = Z0; p.Z1 = Z0;
        p.bk[0] = 0; p.bk[1] = 1024; p.nsec = 2; p.ldb = 2048; p.N = 1024; p.spsl = 5;
        p.relu = 0; p.zmode = 0;
        launch(p, 16, 1);
    }
    combine4<<<EW, 256, 0, stream>>>(Z0, rnn4, F1, F2, F3, R4, R4h);
    // 6) hg = relu(concat(R1..R4) @ W_hg^T) (1-pass, all pre-split); g
    conv(W_hg, WS, nullptr, NWg, nullptr, nullptr, nullptr, 0);
    {
        GemmArgs p{};
        p.A0[0] = S1(R1h, nullptr, 1024); p.A0[1] = S1(R2h, nullptr, 1024);
        p.A0[2] = S1(R3h, nullptr, 1024); p.A0[3] = S1(R4h, nullptr, 1024);
        p.A1[0] = p.A0[0]; p.A1[1] = p.A0[1]; p.A1[2] = p.A0[2]; p.A1[3] = p.A0[3];
        p.B0h = WS; p.B1h = WS;
        p.bias0 = bhg; p.bias1 = bhg;
        p.Z0 = HGF; p.Z1 = HGF;
        p.bk[0] = 0; p.bk[1] = 1024; p.bk[2] = 2048; p.bk[3] = 3072;
        p.nsec = 4; p.ldb = 4096; p.N = 1024; p.spsl = 5;
        p.relu = 1; p.zmode = 0;
        launch(p, 16, 1);
    }
    gemv_g4<<<GV, 256, 0, stream>>>(HGF, W_g, bg, G4);
    // 7) gated (bf16 hi at ws[0,32)); hctpi (1-pass) -> HCTFh bf16
    gated_k<<<dim3(16384), 256, 0, stream>>>(R1, G4, GATEDh);
    conv(W_hct, WS, nullptr, NWg, nullptr, nullptr, nullptr, 0);
    {
        GemmArgs p{};
        p.A0[0] = S1(GATEDh, nullptr, 4096); p.A1[0] = p.A0[0];
        p.B0h = WS; p.B1h = WS;
        p.bias0 = bhct; p.bias1 = bhct;
        p.Zh0 = HCTFh; p.Zh1 = HCTFh;
        p.bk[0] = 0; p.nsec = 1; p.ldb = 4096; p.N = 1024; p.spsl = 7;
        p.relu = 1; p.zmode = 1;
        launch(p, 16, 1);
    }
    // 8) ctpi = log_softmax(hctpi @ W_ct^T + b)
    conv(W_ct, WS, nullptr, NWct, nullptr, nullptr, nullptr, 0);
    {
        GemmArgs p{};
        p.A0[0] = S1(HCTFh, nullptr, 1024); p.A1[0] = p.A0[0];
        p.B0h = WS; p.B1h = WS;
        p.bias0 = bct; p.bias1 = bct;
        p.Z0 = ZC; p.Z1 = ZC;
        p.bk[0] = 0; p.nsec = 1; p.ldb = 1024; p.N = 256; p.spsl = 5;
        p.relu = 0; p.zmode = 0;
        launch(p, 4, 1);
    }
    logsoftmax_k<<<GV, 256, 0, stream>>>(ZC, out);
}